// Round 4
// baseline (136.794 us; speedup 1.0000x reference)
//
#include <hip/hip_runtime.h>
#include <math.h>

// Problem constants
constexpr int R_ = 8;
constexpr int B_ = 16;
constexpr int D_ = 32;
constexpr int H_ = 128;
constexpr int N_ = 2048;
constexpr int F_ = 256;
constexpr int O_ = 64;               // 2*D
constexpr float HLP_ = 0.9189385332046727f;

typedef float f32x4 __attribute__((ext_vector_type(4)));
typedef short bf16x8 __attribute__((ext_vector_type(8)));

// Pack two fp32 -> one dword holding two bf16 (round-half-up via +0x8000,
// then v_perm grabs the two high halves in one instruction).
__device__ __forceinline__ unsigned pk2(float lo, float hi) {
    unsigned a = __builtin_bit_cast(unsigned, lo) + 0x8000u;
    unsigned b = __builtin_bit_cast(unsigned, hi) + 0x8000u;
    return __builtin_amdgcn_perm(b, a, 0x07060302);   // {a.b2,a.b3,b.b2,b.b3}
}

// ---------------------------------------------------------------------------
// Pack kernel: W*M -> bf16 A-fragments (weights are the MFMA A operand).
// A-frag (mt,kt), lane l=(q,c), j:  element Wm[kt*32 + q*8 + j][mt*16 + c].
// Coalesced float4 loads -> LDS tile (rotation swizzle) -> b128 frag stores.
// Grid: 1152 blocks; bid<128: L1 (K=32,Mo=128); <640: L2 slabs (rb,kt);
// else L3 slabs (Mo=64).
// ---------------------------------------------------------------------------
__global__ __launch_bounds__(256, 4)
void pack_w(const float* __restrict__ W1, const float* __restrict__ M1,
            const float* __restrict__ W2, const float* __restrict__ M2,
            const float* __restrict__ W3, const float* __restrict__ M3,
            unsigned short* __restrict__ P1, unsigned short* __restrict__ P2,
            unsigned short* __restrict__ P3)
{
    __shared__ __align__(16) unsigned short tile[32 * 128];  // 8 KB max
    const int bid = blockIdx.x;
    const int t   = threadIdx.x;
    const float *Wsrc, *Msrc;
    unsigned short* dst;
    int Mo, msh, frags;
    if (bid < 128) {
        int rb = bid;
        Wsrc = W1 + (size_t)rb * 32 * 128;
        Msrc = M1 + (size_t)rb * 32 * 128;
        dst  = P1 + (size_t)rb * 8 * 512;
        Mo = 128; msh = 7; frags = 8;
    } else if (bid < 640) {
        int s = bid - 128, rb = s >> 2, kt = s & 3;
        Wsrc = W2 + (size_t)rb * 128 * 128 + (size_t)kt * 32 * 128;
        Msrc = M2 + (size_t)rb * 128 * 128 + (size_t)kt * 32 * 128;
        dst  = P2 + (size_t)(rb * 32 + kt * 8) * 512;
        Mo = 128; msh = 7; frags = 8;
    } else {
        int s = bid - 640, rb = s >> 2, kt = s & 3;
        Wsrc = W3 + (size_t)rb * 128 * 64 + (size_t)kt * 32 * 64;
        Msrc = M3 + (size_t)rb * 128 * 64 + (size_t)kt * 32 * 64;
        dst  = P3 + (size_t)(rb * 16 + kt * 4) * 512;
        Mo = 64; msh = 6; frags = 4;
    }
    const int e4 = (32 << msh) >> 2;       // float4 count: 1024 or 512
    for (int i = t; i < e4; i += 256) {
        float4 wv = ((const float4*)Wsrc)[i];
        float4 mv = ((const float4*)Msrc)[i];
        unsigned lo = pk2(wv.x * mv.x, wv.y * mv.y);
        unsigned hi = pk2(wv.z * mv.z, wv.w * mv.w);
        int k = (i << 2) >> msh;
        int m = (i << 2) & (Mo - 1);
        int mr = (m + ((k >> 3) << 4)) & (Mo - 1);   // rotate cols by 16 per k-octet
        *(uint2*)&tile[k * Mo + mr] = make_uint2(lo, hi);
    }
    __syncthreads();
    const int no = frags * 64;             // lane-octets: 512 or 256
    for (int o = t; o < no; o += 256) {
        int mt = o >> 6, l = o & 63, cc = l & 15, qq = l >> 4;
        unsigned short v[8];
        int colr = ((mt * 16 + cc) + (qq << 4)) & (Mo - 1);  // same rotation (row octet = qq)
#pragma unroll
        for (int j = 0; j < 8; ++j)
            v[j] = tile[(qq * 8 + j) * Mo + colr];
        *(uint4*)(dst + (size_t)(mt * 64 + l) * 8) = *(uint4*)v;
    }
}

// ---------------------------------------------------------------------------
// Main kernel (operand-swapped): C[h][n] = Wm^T-as-A  x  act-as-B.
// 2048 blocks = 128 networks x 16 chunks (128 samples). 512 threads = 8 waves.
// wave w: wm = w&1 (out-feature half), wn = w>>1 (sample quarter, nt pair).
// Activations in LDS in B-frag layout [nt*4+kt][lane][8] bf16; the MFMA C
// layout writes straight into it with b64 stores (no transpose shuffles).
// ---------------------------------------------------------------------------
__global__ __launch_bounds__(512, 4)
void flow_mfma(const float* __restrict__ x, const int* __restrict__ ridx,
               const unsigned short* __restrict__ P1,
               const unsigned short* __restrict__ P2,
               const unsigned short* __restrict__ P3,
               float* __restrict__ out)
{
    __shared__ __align__(16) unsigned short xB [8 * 64 * 8];    //  8 KB [nt][lane][j]
    __shared__ __align__(16) unsigned short h1B[32 * 64 * 8];   // 32 KB [nt*4+kt][lane][j]
    __shared__ __align__(16) unsigned short h2B[32 * 64 * 8];   // 32 KB
    __shared__ float part[8][2][16];                            // 1 KB

    const int bid = blockIdx.x;
    const int rb  = bid >> 4;
    const int n0  = (bid & 15) * 128;
    const int r   = rb >> 4;

    const int t    = threadIdx.x;
    const int lane = t & 63;
    const int w    = t >> 6;
    const int wm   = w & 1;
    const int wn   = w >> 1;
    const int q    = lane >> 4;
    const int c    = lane & 15;

    // prefetch G1 A-frags (layer-1 weights) while gathering x
    bf16x8 a1[4];
#pragma unroll
    for (int i = 0; i < 4; ++i)
        a1[i] = *(const bf16x8*)(P1 + ((size_t)(rb * 8 + wm * 4 + i) * 64 + lane) * 8);

    // ---- gather x -> B-frags (lane n = sample, k = d octets) ----
    {
        int nl = t >> 2;                 // 0..127
        int dq = t & 3;                  // d-octet
        const int* rp = ridx + r * 32 + dq * 8;
        int cols[8];
#pragma unroll
        for (int j = 0; j < 8; ++j) cols[j] = rp[j];
        const float* xrow = x + (size_t)(n0 + nl) * F_;
        unsigned pk[4];
#pragma unroll
        for (int j = 0; j < 4; ++j)
            pk[j] = pk2(xrow[cols[2 * j]], xrow[cols[2 * j + 1]]);
        int slot = ((nl >> 4) * 64) + (dq << 4) + (nl & 15);
        *(uint4*)&xB[slot * 8] = make_uint4(pk[0], pk[1], pk[2], pk[3]);
    }
    __syncthreads();

    // ---- GEMM1: C1[h][n], K=32 (one kt) ----
    {
        bf16x8 b1[2];
#pragma unroll
        for (int jn = 0; jn < 2; ++jn)
            b1[jn] = *(bf16x8*)&xB[((wn * 2 + jn) * 64 + lane) * 8];
        f32x4 z = {0.f, 0.f, 0.f, 0.f};
        f32x4 acc[4][2];
#pragma unroll
        for (int i = 0; i < 4; ++i)
#pragma unroll
            for (int jn = 0; jn < 2; ++jn)
                acc[i][jn] = __builtin_amdgcn_mfma_f32_16x16x32_bf16(a1[i], b1[jn], z, 0, 0, 0);
        // store h1 (relu+bf16): lane's 4 regs = 4 consecutive k at fixed n -> b64
#pragma unroll
        for (int i = 0; i < 4; ++i) {
            int mt  = wm * 4 + i;
            int ktw = mt >> 1;
            int qw  = (2 * mt + (q >> 1)) & 3;
            int j0h = (q & 1) * 4;
#pragma unroll
            for (int jn = 0; jn < 2; ++jn) {
                int nt = wn * 2 + jn;
                unsigned lo = pk2(fmaxf(acc[i][jn][0], 0.f), fmaxf(acc[i][jn][1], 0.f));
                unsigned hi = pk2(fmaxf(acc[i][jn][2], 0.f), fmaxf(acc[i][jn][3], 0.f));
                *(uint2*)&h1B[(((nt * 4 + ktw) * 64) + qw * 16 + c) * 8 + j0h] = make_uint2(lo, hi);
            }
        }
    }
    // prefetch G2 kt=0 A-frags before the barrier
    bf16x8 a2[4];
#pragma unroll
    for (int i = 0; i < 4; ++i)
        a2[i] = *(const bf16x8*)(P2 + ((size_t)(rb * 32 + wm * 4 + i) * 64 + lane) * 8);
    __syncthreads();

    // ---- GEMM2: C2[h2][n], K=128 ----
    f32x4 acc2[4][2];
#pragma unroll
    for (int i = 0; i < 4; ++i)
#pragma unroll
        for (int jn = 0; jn < 2; ++jn) acc2[i][jn] = (f32x4){0.f, 0.f, 0.f, 0.f};
#pragma unroll
    for (int kt = 0; kt < 4; ++kt) {
        bf16x8 bb[2];
#pragma unroll
        for (int jn = 0; jn < 2; ++jn)
            bb[jn] = *(bf16x8*)&h1B[(((wn * 2 + jn) * 4 + kt) * 64 + lane) * 8];
        bf16x8 an[4];
        if (kt < 3) {
#pragma unroll
            for (int i = 0; i < 4; ++i)
                an[i] = *(const bf16x8*)(P2 + ((size_t)(rb * 32 + (kt + 1) * 8 + wm * 4 + i) * 64 + lane) * 8);
        }
#pragma unroll
        for (int i = 0; i < 4; ++i)
#pragma unroll
            for (int jn = 0; jn < 2; ++jn)
                acc2[i][jn] = __builtin_amdgcn_mfma_f32_16x16x32_bf16(a2[i], bb[jn], acc2[i][jn], 0, 0, 0);
        if (kt < 3) {
#pragma unroll
            for (int i = 0; i < 4; ++i) a2[i] = an[i];
        }
    }
    // prefetch G3 kt=0 A-frags (latency hidden by stores + barrier)
    bf16x8 a3[2];
#pragma unroll
    for (int im = 0; im < 2; ++im)
        a3[im] = *(const bf16x8*)(P3 + ((size_t)(rb * 16 + wm * 2 + im) * 64 + lane) * 8);
    // store h2
#pragma unroll
    for (int i = 0; i < 4; ++i) {
        int mt  = wm * 4 + i;
        int ktw = mt >> 1;
        int qw  = (2 * mt + (q >> 1)) & 3;
        int j0h = (q & 1) * 4;
#pragma unroll
        for (int jn = 0; jn < 2; ++jn) {
            int nt = wn * 2 + jn;
            unsigned lo = pk2(fmaxf(acc2[i][jn][0], 0.f), fmaxf(acc2[i][jn][1], 0.f));
            unsigned hi = pk2(fmaxf(acc2[i][jn][2], 0.f), fmaxf(acc2[i][jn][3], 0.f));
            *(uint2*)&h2B[(((nt * 4 + ktw) * 64) + qw * 16 + c) * 8 + j0h] = make_uint2(lo, hi);
        }
    }
    __syncthreads();

    // ---- GEMM3: C3[o][n], o=2d+p; lane's 4 regs = two complete (shift,ls) pairs ----
    {
        f32x4 acc3[2][2];
#pragma unroll
        for (int im = 0; im < 2; ++im)
#pragma unroll
            for (int jn = 0; jn < 2; ++jn) acc3[im][jn] = (f32x4){0.f, 0.f, 0.f, 0.f};
#pragma unroll
        for (int kt = 0; kt < 4; ++kt) {
            bf16x8 bb[2];
#pragma unroll
            for (int jn = 0; jn < 2; ++jn)
                bb[jn] = *(bf16x8*)&h2B[(((wn * 2 + jn) * 4 + kt) * 64 + lane) * 8];
            bf16x8 an[2];
            if (kt < 3) {
#pragma unroll
                for (int im = 0; im < 2; ++im)
                    an[im] = *(const bf16x8*)(P3 + ((size_t)(rb * 16 + (kt + 1) * 4 + wm * 2 + im) * 64 + lane) * 8);
            }
#pragma unroll
            for (int im = 0; im < 2; ++im)
#pragma unroll
                for (int jn = 0; jn < 2; ++jn)
                    acc3[im][jn] = __builtin_amdgcn_mfma_f32_16x16x32_bf16(a3[im], bb[jn], acc3[im][jn], 0, 0, 0);
            if (kt < 3) { a3[0] = an[0]; a3[1] = an[1]; }
        }
        // epilogue: o = mt3*16 + q*4 + reg -> regs {0,1}=(shift,ls) d0, {2,3}= d0+1
        float pll[2] = {0.f, 0.f};
#pragma unroll
        for (int im = 0; im < 2; ++im) {
            int mt3 = wm * 2 + im;
            int d0  = mt3 * 8 + q * 2;
            int col0 = ridx[r * 32 + d0];
            int col1 = ridx[r * 32 + d0 + 1];
#pragma unroll
            for (int jn = 0; jn < 2; ++jn) {
                int n = n0 + (wn * 2 + jn) * 16 + c;
                const float* xr_ = x + (size_t)n * F_;
                float x0 = xr_[col0], x1 = xr_[col1];
                float sh0 = acc3[im][jn][0], ls0 = acc3[im][jn][1];
                float sh1 = acc3[im][jn][2], ls1 = acc3[im][jn][3];
                float u0 = (x0 - sh0) * __expf(-ls0);
                float u1 = (x1 - sh1) * __expf(-ls1);
                pll[jn] += fmaf(-0.5f * u0, u0, -HLP_ - ls0) + fmaf(-0.5f * u1, u1, -HLP_ - ls1);
            }
        }
#pragma unroll
        for (int jn = 0; jn < 2; ++jn) {
            pll[jn] += __shfl_xor(pll[jn], 16, 64);
            pll[jn] += __shfl_xor(pll[jn], 32, 64);
        }
        if (q == 0) {
            part[w][0][c] = pll[0];
            part[w][1][c] = pll[1];
        }
    }
    __syncthreads();

    if (t < 128) {
        int wnf = t >> 5, jnf = (t >> 4) & 1, cf = t & 15;
        float s = part[wnf * 2 + 0][jnf][cf] + part[wnf * 2 + 1][jnf][cf];
        out[(size_t)(n0 + t) * (R_ * B_) + rb] = s;
    }
}

// ---------------------------------------------------------------------------
// Fallback (ws too small): fp32 register-tiled kernel, masks on the fly.
// ---------------------------------------------------------------------------
__global__ __launch_bounds__(512, 2)
void flow_fb(const float* __restrict__ x,
             const float* __restrict__ W1, const float* __restrict__ W2,
             const float* __restrict__ W3,
             const float* __restrict__ M1, const float* __restrict__ M2,
             const float* __restrict__ M3,
             const int* __restrict__ ridx, float* __restrict__ out)
{
    __shared__ float xT[D_][132];
    __shared__ float h1T[H_][128];
    __shared__ float h2T[H_][128];
    __shared__ float part[16][132];
    const int bid = blockIdx.x, rb = bid >> 4, r = rb >> 4;
    const int n0 = (bid & 15) * 128;
    const int t = threadIdx.x, tr = t >> 4, tc = t & 15;
    const int tr4 = tr * 4, tc8 = tc * 8, tc4 = tc * 4;
    {
        int d = t & 31, rg = t >> 5;
        int col = ridx[r * D_ + d];
        const float* xp = x + (size_t)(n0 + rg * 8) * F_ + col;
#pragma unroll
        for (int i = 0; i < 8; ++i) xT[d][rg * 8 + i] = xp[i * F_];
    }
    __syncthreads();
    {
        float acc[4][8];
#pragma unroll
        for (int i = 0; i < 4; ++i)
#pragma unroll
            for (int j = 0; j < 8; ++j) acc[i][j] = 0.f;
        const float* Wb = W1 + (size_t)rb * D_ * H_;
        const float* Mb = M1 + (size_t)rb * D_ * H_;
        for (int k = 0; k < D_; ++k) {
            float a[4]; *(float4*)a = *(const float4*)&xT[k][tr4];
            const float* wr = Wb + k * H_ + tc8;
            const float* mr = Mb + k * H_ + tc8;
#pragma unroll
            for (int j = 0; j < 8; ++j) {
                float wv = wr[j] * mr[j];
#pragma unroll
                for (int i = 0; i < 4; ++i) acc[i][j] = fmaf(a[i], wv, acc[i][j]);
            }
        }
#pragma unroll
        for (int j = 0; j < 8; ++j) {
            float4 v = make_float4(fmaxf(acc[0][j], 0.f), fmaxf(acc[1][j], 0.f),
                                   fmaxf(acc[2][j], 0.f), fmaxf(acc[3][j], 0.f));
            *(float4*)&h1T[tc8 + j][tr4] = v;
        }
    }
    __syncthreads();
    {
        float acc[4][8];
#pragma unroll
        for (int i = 0; i < 4; ++i)
#pragma unroll
            for (int j = 0; j < 8; ++j) acc[i][j] = 0.f;
        const float* Wb = W2 + (size_t)rb * H_ * H_;
        const float* Mb = M2 + (size_t)rb * H_ * H_;
        for (int k = 0; k < H_; ++k) {
            float a[4]; *(float4*)a = *(const float4*)&h1T[k][tr4];
            const float* wr = Wb + k * H_ + tc8;
            const float* mr = Mb + k * H_ + tc8;
#pragma unroll
            for (int j = 0; j < 8; ++j) {
                float wv = wr[j] * mr[j];
#pragma unroll
                for (int i = 0; i < 4; ++i) acc[i][j] = fmaf(a[i], wv, acc[i][j]);
            }
        }
#pragma unroll
        for (int j = 0; j < 8; ++j) {
            float4 v = make_float4(fmaxf(acc[0][j], 0.f), fmaxf(acc[1][j], 0.f),
                                   fmaxf(acc[2][j], 0.f), fmaxf(acc[3][j], 0.f));
            *(float4*)&h2T[tc8 + j][tr4] = v;
        }
    }
    __syncthreads();
    {
        float acc[4][4];
#pragma unroll
        for (int i = 0; i < 4; ++i)
#pragma unroll
            for (int j = 0; j < 4; ++j) acc[i][j] = 0.f;
        const float* Wb = W3 + (size_t)rb * H_ * O_;
        const float* Mb = M3 + (size_t)rb * H_ * O_;
        for (int k = 0; k < H_; ++k) {
            float a[4]; *(float4*)a = *(const float4*)&h2T[k][tr4];
            const float* wr = Wb + k * O_ + tc4;
            const float* mr = Mb + k * O_ + tc4;
#pragma unroll
            for (int j = 0; j < 4; ++j) {
                float wv = wr[j] * mr[j];
#pragma unroll
                for (int i = 0; i < 4; ++i) acc[i][j] = fmaf(a[i], wv, acc[i][j]);
            }
        }
#pragma unroll
        for (int i = 0; i < 4; ++i) {
            int row = tr4 + i;
            float ll = 0.f;
#pragma unroll
            for (int qd = 0; qd < 2; ++qd) {
                float shift = acc[i][2 * qd], ls = acc[i][2 * qd + 1];
                float xvv = xT[2 * tc + qd][row];
                float u = (xvv - shift) * __expf(-ls);
                ll = fmaf(-0.5f * u, u, ll - HLP_ - ls);
            }
            part[tc][row] = ll;
        }
    }
    __syncthreads();
    if (t < 128) {
        float s = 0.f;
#pragma unroll
        for (int cc = 0; cc < 16; ++cc) s += part[cc][t];
        out[(size_t)(n0 + t) * (R_ * B_) + rb] = s;
    }
}

extern "C" void kernel_launch(void* const* d_in, const int* in_sizes, int n_in,
                              void* d_out, int out_size, void* d_ws, size_t ws_size,
                              hipStream_t stream) {
    const float* x   = (const float*)d_in[0];
    const float* W1  = (const float*)d_in[1];
    const float* W2  = (const float*)d_in[2];
    const float* W3  = (const float*)d_in[3];
    const float* M1  = (const float*)d_in[4];
    const float* M2  = (const float*)d_in[5];
    const float* M3  = (const float*)d_in[6];
    const int*  ridx = (const int*)d_in[7];
    float* out = (float*)d_out;

    const size_t s1 = (size_t)128 * 8  * 512;   // P1 shorts
    const size_t s2 = (size_t)128 * 32 * 512;   // P2 shorts
    const size_t s3 = (size_t)128 * 16 * 512;   // P3 shorts
    const size_t need = (s1 + s2 + s3) * sizeof(unsigned short);   // 7 MB

    if (d_ws != nullptr && ws_size >= need) {
        unsigned short* P1 = (unsigned short*)d_ws;
        unsigned short* P2 = P1 + s1;
        unsigned short* P3 = P2 + s2;
        pack_w<<<dim3(1152), dim3(256), 0, stream>>>(W1, M1, W2, M2, W3, M3, P1, P2, P3);
        flow_mfma<<<dim3(2048), dim3(512), 0, stream>>>(x, ridx, P1, P2, P3, out);
    } else {
        flow_fb<<<dim3(2048), dim3(512), 0, stream>>>(x, W1, W2, W3, M1, M2, M3, ridx, out);
    }
}

// Round 5
// 111.940 us; speedup vs baseline: 1.2220x; 1.2220x over previous
//
#include <hip/hip_runtime.h>
#include <math.h>

// Problem constants
constexpr int R_ = 8;
constexpr int B_ = 16;
constexpr int D_ = 32;
constexpr int H_ = 128;
constexpr int N_ = 2048;
constexpr int F_ = 256;
constexpr int O_ = 64;               // 2*D
constexpr float HLP_ = 0.9189385332046727f;

typedef float f32x4 __attribute__((ext_vector_type(4)));
typedef short bf16x8 __attribute__((ext_vector_type(8)));

// Pack two fp32 -> one dword of two bf16 (round-half-up, v_perm for hi halves).
__device__ __forceinline__ unsigned pk2(float lo, float hi) {
    unsigned a = __builtin_bit_cast(unsigned, lo) + 0x8000u;
    unsigned b = __builtin_bit_cast(unsigned, hi) + 0x8000u;
    return __builtin_amdgcn_perm(b, a, 0x07060302);   // {a.b2,a.b3,b.b2,b.b3}
}

// ---------------------------------------------------------------------------
// Single fused kernel. 256 blocks = 128 networks x 2 halves; 512 threads
// (8 waves, 1 block/CU). Phase 1: pack this network's masked weights into
// per-lane MFMA A-fragments held in REGISTERS (112 VGPR/lane), staged via a
// double-buffered LDS transpose tile. Phase 2: loop 8 chunks of 128 samples;
// per chunk all GEMM traffic is LDS-only (weights in regs), x gathered one
// chunk ahead into registers.
// A-frag convention (operand-swap GEMM: C[h][n] = Wm^T x act):
//   lane (q=lane>>4, c=lane&15), j in 0..7 holds Wm[k = kt*32+q*8+j][m = mt*16+c].
// Activations in LDS in B-frag layout [nt*4+kt][lane][8] (R4-verified).
// ---------------------------------------------------------------------------
__global__ __launch_bounds__(512, 2)
void flow_all(const float* __restrict__ x,
              const float* __restrict__ W1, const float* __restrict__ W2,
              const float* __restrict__ W3,
              const float* __restrict__ M1, const float* __restrict__ M2,
              const float* __restrict__ M3,
              const int* __restrict__ ridx,
              float* __restrict__ out)
{
    // stage rows: 128-wide slabs use stride 40 shorts (80 B, 16B-aligned);
    // 64-wide (W3) super-slabs use stride 72 shorts (144 B, 16B-aligned).
    __shared__ __align__(16) unsigned short stg[2][5120];   // 20 KB
    __shared__ __align__(16) unsigned short xB [8 * 64 * 8];    //  8 KB
    __shared__ float xF[32][129];                               // 16.1 KB fp32 x for epilogue
    __shared__ __align__(16) unsigned short h1B[32 * 64 * 8];   // 32 KB
    __shared__ __align__(16) unsigned short h2B[32 * 64 * 8];   // 32 KB
    __shared__ float part[8][2][16];                            // 1 KB

    const int bid  = blockIdx.x;
    const int rb   = bid >> 1;           // network 0..127
    const int half = bid & 1;            // which 8 chunks
    const int r    = rb >> 4;

    const int t    = threadIdx.x;
    const int lane = t & 63;
    const int w    = t >> 6;
    const int wm   = w & 1;
    const int wn   = w >> 1;
    const int q    = lane >> 4;
    const int c    = lane & 15;

    // ---- gather-thread mapping + chunk-0 prefetch ----
    const int nl = t >> 2;               // sample row within chunk (0..127)
    const int dq = t & 3;                // d-octet
    int cols[8];
#pragma unroll
    for (int j = 0; j < 8; ++j) cols[j] = ridx[r * 32 + dq * 8 + j];
    float gx[8];
    {
        const float* xrow = x + (size_t)(half * 8 * 128 + nl) * F_;
#pragma unroll
        for (int j = 0; j < 8; ++j) gx[j] = xrow[cols[j]];
    }

    // ---- phase 1: pack masked weights into register A-frags ----
    const float* W1b = W1 + (size_t)rb * 32 * 128;
    const float* M1b = M1 + (size_t)rb * 32 * 128;
    const float* W2b = W2 + (size_t)rb * 128 * 128;
    const float* M2s = M2;               // M2 identical for all (r,b) networks
    const float* W3b = W3 + (size_t)rb * 128 * 64;
    const float* M3b = M3 + (size_t)rb * 128 * 64;

    const int pm = t & 127, pkq = t >> 7;   // 128-wide slab mapping
    const int qm = t & 63,  qkk = t >> 6;   // 64-wide super-slab mapping

    bf16x8 a1[4], a2[4][4], a3[4][2];
    float wv0[8], mv0[8], wv1[8], mv1[8];

    auto ld128 = [&](const float* Wp, const float* Mp, float* wv, float* mv) {
        const float* wp = Wp + (size_t)(pkq * 8) * 128 + pm;
        const float* mp = Mp + (size_t)(pkq * 8) * 128 + pm;
#pragma unroll
        for (int e = 0; e < 8; ++e) { wv[e] = wp[(size_t)e * 128]; mv[e] = mp[(size_t)e * 128]; }
    };
    auto ld64s = [&](const float* Wp, const float* Mp, int ss, float* wv, float* mv) {
        const float* wp = Wp + (size_t)(ss * 64 + qkk * 8) * 64 + qm;
        const float* mp = Mp + (size_t)(ss * 64 + qkk * 8) * 64 + qm;
#pragma unroll
        for (int e = 0; e < 8; ++e) { wv[e] = wp[(size_t)e * 64]; mv[e] = mp[(size_t)e * 64]; }
    };
    auto pack128 = [&](unsigned short* st, const float* wv, const float* mv) {
        unsigned u0 = pk2(wv[0]*mv[0], wv[1]*mv[1]);
        unsigned u1 = pk2(wv[2]*mv[2], wv[3]*mv[3]);
        unsigned u2 = pk2(wv[4]*mv[4], wv[5]*mv[5]);
        unsigned u3 = pk2(wv[6]*mv[6], wv[7]*mv[7]);
        *(uint4*)&st[pm * 40 + pkq * 8] = make_uint4(u0, u1, u2, u3);
    };
    auto pack64 = [&](unsigned short* st, const float* wv, const float* mv) {
        unsigned u0 = pk2(wv[0]*mv[0], wv[1]*mv[1]);
        unsigned u1 = pk2(wv[2]*mv[2], wv[3]*mv[3]);
        unsigned u2 = pk2(wv[4]*mv[4], wv[5]*mv[5]);
        unsigned u3 = pk2(wv[6]*mv[6], wv[7]*mv[7]);
        *(uint4*)&st[qm * 72 + qkk * 8] = make_uint4(u0, u1, u2, u3);
    };
    auto frag128 = [&](const unsigned short* st, int mt) -> bf16x8 {
        return *(const bf16x8*)&st[(mt * 16 + c) * 40 + q * 8];
    };
    auto frag64 = [&](const unsigned short* st, int im, int klo) -> bf16x8 {
        return *(const bf16x8*)&st[((wm * 2 + im) * 16 + c) * 72 + klo + q * 8];
    };

    ld128(W1b, M1b, wv0, mv0);                       // S0 in flight
    ld128(W2b, M2s, wv1, mv1);                       // S1 in flight
    pack128(stg[0], wv0, mv0); __syncthreads();
#pragma unroll
    for (int i = 0; i < 4; ++i) a1[i] = frag128(stg[0], wm * 4 + i);

    ld128(W2b + 32 * 128, M2s + 32 * 128, wv0, mv0); // S2
    pack128(stg[1], wv1, mv1); __syncthreads();
#pragma unroll
    for (int i = 0; i < 4; ++i) a2[0][i] = frag128(stg[1], wm * 4 + i);

    ld128(W2b + 64 * 128, M2s + 64 * 128, wv1, mv1); // S3
    pack128(stg[0], wv0, mv0); __syncthreads();
#pragma unroll
    for (int i = 0; i < 4; ++i) a2[1][i] = frag128(stg[0], wm * 4 + i);

    ld128(W2b + 96 * 128, M2s + 96 * 128, wv0, mv0); // S4
    pack128(stg[1], wv1, mv1); __syncthreads();
#pragma unroll
    for (int i = 0; i < 4; ++i) a2[2][i] = frag128(stg[1], wm * 4 + i);

    ld64s(W3b, M3b, 0, wv1, mv1);                    // S5 (W3 k 0..63)
    pack128(stg[0], wv0, mv0); __syncthreads();
#pragma unroll
    for (int i = 0; i < 4; ++i) a2[3][i] = frag128(stg[0], wm * 4 + i);

    ld64s(W3b, M3b, 1, wv0, mv0);                    // S6 (W3 k 64..127)
    pack64(stg[1], wv1, mv1); __syncthreads();
#pragma unroll
    for (int im = 0; im < 2; ++im) {
        a3[0][im] = frag64(stg[1], im, 0);
        a3[1][im] = frag64(stg[1], im, 32);
    }
    pack64(stg[0], wv0, mv0); __syncthreads();
#pragma unroll
    for (int im = 0; im < 2; ++im) {
        a3[2][im] = frag64(stg[0], im, 0);
        a3[3][im] = frag64(stg[0], im, 32);
    }

    // ---- phase 2: chunk loop ----
#pragma unroll 1
    for (int cc = 0; cc < 8; ++cc) {
        const int n0 = (half * 8 + cc) * 128;

        // publish gathered x for this chunk: bf16 B-frags + fp32 copy
        {
            unsigned p0 = pk2(gx[0], gx[1]), p1 = pk2(gx[2], gx[3]);
            unsigned p2 = pk2(gx[4], gx[5]), p3 = pk2(gx[6], gx[7]);
            int slot = ((nl >> 4) * 64) + (dq << 4) + (nl & 15);
            *(uint4*)&xB[slot * 8] = make_uint4(p0, p1, p2, p3);
#pragma unroll
            for (int j = 0; j < 8; ++j) xF[dq * 8 + j][nl] = gx[j];
        }
        __syncthreads();                             // sync1: xB/xF/part(cc-1) visible

        if (cc > 0 && t < 128) {                     // out for chunk cc-1
            int wnf = t >> 5, jnf = (t >> 4) & 1, cf = t & 15;
            float s = part[wnf * 2 + 0][jnf][cf] + part[wnf * 2 + 1][jnf][cf];
            out[(size_t)(n0 - 128 + t) * (R_ * B_) + rb] = s;
        }

        // ---- GEMM1: h1 = relu(Wm1^T x)  K=32 ----
        {
            bf16x8 b10 = *(bf16x8*)&xB[((wn * 2 + 0) * 64 + lane) * 8];
            bf16x8 b11 = *(bf16x8*)&xB[((wn * 2 + 1) * 64 + lane) * 8];
            f32x4 z = {0.f, 0.f, 0.f, 0.f};
            f32x4 acc[4][2];
#pragma unroll
            for (int i = 0; i < 4; ++i) {
                acc[i][0] = __builtin_amdgcn_mfma_f32_16x16x32_bf16(a1[i], b10, z, 0, 0, 0);
                acc[i][1] = __builtin_amdgcn_mfma_f32_16x16x32_bf16(a1[i], b11, z, 0, 0, 0);
            }
#pragma unroll
            for (int i = 0; i < 4; ++i) {
                int mt = wm * 4 + i;
                int ktw = mt >> 1;
                int qw  = (2 * mt + (q >> 1)) & 3;
                int j0h = (q & 1) * 4;
#pragma unroll
                for (int jn = 0; jn < 2; ++jn) {
                    int nt = wn * 2 + jn;
                    unsigned lo = pk2(fmaxf(acc[i][jn][0], 0.f), fmaxf(acc[i][jn][1], 0.f));
                    unsigned hi = pk2(fmaxf(acc[i][jn][2], 0.f), fmaxf(acc[i][jn][3], 0.f));
                    *(uint2*)&h1B[(((nt * 4 + ktw) * 64) + qw * 16 + c) * 8 + j0h] = make_uint2(lo, hi);
                }
            }
        }
        // prefetch next chunk's gather into registers
        if (cc < 7) {
            const float* xrow = x + (size_t)((half * 8 + cc + 1) * 128 + nl) * F_;
#pragma unroll
            for (int j = 0; j < 8; ++j) gx[j] = xrow[cols[j]];
        }
        __syncthreads();                             // sync2: h1B ready

        // ---- GEMM2: h2 = relu(Wm2^T h1)  K=128 ----
        f32x4 acc2[4][2];
#pragma unroll
        for (int i = 0; i < 4; ++i) { acc2[i][0] = (f32x4){0.f,0.f,0.f,0.f}; acc2[i][1] = (f32x4){0.f,0.f,0.f,0.f}; }
#pragma unroll
        for (int kt = 0; kt < 4; ++kt) {
            bf16x8 bb0 = *(bf16x8*)&h1B[(((wn * 2 + 0) * 4 + kt) * 64 + lane) * 8];
            bf16x8 bb1 = *(bf16x8*)&h1B[(((wn * 2 + 1) * 4 + kt) * 64 + lane) * 8];
#pragma unroll
            for (int i = 0; i < 4; ++i) {
                acc2[i][0] = __builtin_amdgcn_mfma_f32_16x16x32_bf16(a2[kt][i], bb0, acc2[i][0], 0, 0, 0);
                acc2[i][1] = __builtin_amdgcn_mfma_f32_16x16x32_bf16(a2[kt][i], bb1, acc2[i][1], 0, 0, 0);
            }
        }
#pragma unroll
        for (int i = 0; i < 4; ++i) {
            int mt = wm * 4 + i;
            int ktw = mt >> 1;
            int qw  = (2 * mt + (q >> 1)) & 3;
            int j0h = (q & 1) * 4;
#pragma unroll
            for (int jn = 0; jn < 2; ++jn) {
                int nt = wn * 2 + jn;
                unsigned lo = pk2(fmaxf(acc2[i][jn][0], 0.f), fmaxf(acc2[i][jn][1], 0.f));
                unsigned hi = pk2(fmaxf(acc2[i][jn][2], 0.f), fmaxf(acc2[i][jn][3], 0.f));
                *(uint2*)&h2B[(((nt * 4 + ktw) * 64) + qw * 16 + c) * 8 + j0h] = make_uint2(lo, hi);
            }
        }
        // epilogue x values: read from xF BEFORE sync3 (xF overwritten only
        // after every thread passes sync3 and reaches the next loop top)
        float xv[2][2][2];
#pragma unroll
        for (int im = 0; im < 2; ++im) {
            int d0 = (wm * 2 + im) * 8 + q * 2;
#pragma unroll
            for (int jn = 0; jn < 2; ++jn) {
                int rl = (wn * 2 + jn) * 16 + c;
                xv[im][jn][0] = xF[d0][rl];
                xv[im][jn][1] = xF[d0 + 1][rl];
            }
        }
        __syncthreads();                             // sync3: h2B ready

        // ---- GEMM3 + MAF epilogue ----
        f32x4 acc3[2][2];
#pragma unroll
        for (int im = 0; im < 2; ++im) { acc3[im][0] = (f32x4){0.f,0.f,0.f,0.f}; acc3[im][1] = (f32x4){0.f,0.f,0.f,0.f}; }
#pragma unroll
        for (int kt = 0; kt < 4; ++kt) {
            bf16x8 bb0 = *(bf16x8*)&h2B[(((wn * 2 + 0) * 4 + kt) * 64 + lane) * 8];
            bf16x8 bb1 = *(bf16x8*)&h2B[(((wn * 2 + 1) * 4 + kt) * 64 + lane) * 8];
#pragma unroll
            for (int im = 0; im < 2; ++im) {
                acc3[im][0] = __builtin_amdgcn_mfma_f32_16x16x32_bf16(a3[kt][im], bb0, acc3[im][0], 0, 0, 0);
                acc3[im][1] = __builtin_amdgcn_mfma_f32_16x16x32_bf16(a3[kt][im], bb1, acc3[im][1], 0, 0, 0);
            }
        }
        float pll[2] = {0.f, 0.f};
#pragma unroll
        for (int im = 0; im < 2; ++im) {
#pragma unroll
            for (int jn = 0; jn < 2; ++jn) {
                float sh0 = acc3[im][jn][0], ls0 = acc3[im][jn][1];
                float sh1 = acc3[im][jn][2], ls1 = acc3[im][jn][3];
                float u0 = (xv[im][jn][0] - sh0) * __expf(-ls0);
                float u1 = (xv[im][jn][1] - sh1) * __expf(-ls1);
                pll[jn] += fmaf(-0.5f * u0, u0, -HLP_ - ls0) + fmaf(-0.5f * u1, u1, -HLP_ - ls1);
            }
        }
        pll[0] += __shfl_xor(pll[0], 16, 64);  pll[0] += __shfl_xor(pll[0], 32, 64);
        pll[1] += __shfl_xor(pll[1], 16, 64);  pll[1] += __shfl_xor(pll[1], 32, 64);
        if (q == 0) { part[w][0][c] = pll[0]; part[w][1][c] = pll[1]; }
    }
    __syncthreads();
    if (t < 128) {                                   // out for last chunk
        int wnf = t >> 5, jnf = (t >> 4) & 1, cf = t & 15;
        float s = part[wnf * 2 + 0][jnf][cf] + part[wnf * 2 + 1][jnf][cf];
        out[(size_t)((half * 8 + 7) * 128 + t) * (R_ * B_) + rb] = s;
    }
}

extern "C" void kernel_launch(void* const* d_in, const int* in_sizes, int n_in,
                              void* d_out, int out_size, void* d_ws, size_t ws_size,
                              hipStream_t stream) {
    const float* x   = (const float*)d_in[0];
    const float* W1  = (const float*)d_in[1];
    const float* W2  = (const float*)d_in[2];
    const float* W3  = (const float*)d_in[3];
    const float* M1  = (const float*)d_in[4];
    const float* M2  = (const float*)d_in[5];
    const float* M3  = (const float*)d_in[6];
    const int*  ridx = (const int*)d_in[7];
    float* out = (float*)d_out;

    flow_all<<<dim3(256), dim3(512), 0, stream>>>(x, W1, W2, W3, M1, M2, M3, ridx, out);
}

// Round 6
// 109.695 us; speedup vs baseline: 1.2470x; 1.0205x over previous
//
#include <hip/hip_runtime.h>
#include <math.h>

// Problem constants
constexpr int R_ = 8;
constexpr int B_ = 16;
constexpr int D_ = 32;
constexpr int H_ = 128;
constexpr int N_ = 2048;
constexpr int F_ = 256;
constexpr int O_ = 64;               // 2*D
constexpr float HLP_ = 0.9189385332046727f;

typedef float f32x4 __attribute__((ext_vector_type(4)));
typedef short bf16x8 __attribute__((ext_vector_type(8)));
typedef unsigned uint32x4 __attribute__((ext_vector_type(4)));

// Pack two fp32 -> one dword of two bf16 (round-half-up, v_perm for hi halves).
__device__ __forceinline__ unsigned pk2(float lo, float hi) {
    unsigned a = __builtin_bit_cast(unsigned, lo) + 0x8000u;
    unsigned b = __builtin_bit_cast(unsigned, hi) + 0x8000u;
    return __builtin_amdgcn_perm(b, a, 0x07060302);   // {a.b2,a.b3,b.b2,b.b3}
}

// ---------------------------------------------------------------------------
// Single fused kernel, BARRIER-FREE main loop.
// 256 blocks = 128 networks x 2 halves; 512 threads = 8 waves, 1 block/CU.
//
// Phase 1 (one barrier at end): pack W*M -> bf16 MFMA A-frags in LDS.
//   A-frag (mt,kt), lane (q=lane>>4, c=lane&15), j: Wm[kt*32+q*8+j][mt*16+c].
//   W3 columns are PERMUTED: output slot d' holds source d =
//   ((d'>>1)&3)*8 + (d'>>3)*2 + (d'&1), so the epilogue's x for lane (q,c)
//   is exactly its own gathered gx[mt3*2+rr] register (no epilogue loads).
//
// Phase 2 (NO barriers): 4 passes x 2 chunks. Wave w owns samples
//   [w*16, w*16+16) of each chunk and computes ALL features; h1/h2 transpose
//   via per-wave-private LDS (b64 write / b128 read, intra-wave lgkmcnt only).
// ---------------------------------------------------------------------------
__global__ __launch_bounds__(512, 2)
void flow_all(const float* __restrict__ x,
              const float* __restrict__ W1, const float* __restrict__ W2,
              const float* __restrict__ W3,
              const float* __restrict__ M1, const float* __restrict__ M2,
              const float* __restrict__ M3,
              const int* __restrict__ ridx,
              float* __restrict__ out)
{
    __shared__ __align__(16) unsigned short WA1[8  * 64 * 8];   //  8 KB
    __shared__ __align__(16) unsigned short WA2[32 * 64 * 8];   // 32 KB
    __shared__ __align__(16) unsigned short WA3[16 * 64 * 8];   // 16 KB
    __shared__ __align__(16) unsigned short hws[8 * 4096];      // 64 KB (8 KB/wave)

    const int bid  = blockIdx.x;
    const int rb   = bid >> 1;           // network
    const int half = bid & 1;
    const int r    = rb >> 4;

    const int t    = threadIdx.x;
    const int lane = t & 63;
    const int w    = t >> 6;
    const int q    = lane >> 4;
    const int c    = lane & 15;

    unsigned short* hwp = hws + w * 4096;   // per-wave scratch (2 tiles x 4 kt)

    // lane's sample row (within x/out), advanced by 256 per pass, +128 for tile B
    const int nbase = half * 1024 + w * 16 + c;

    // gather columns for this lane's k-octet (d = q*8+j)
    int cols[8];
#pragma unroll
    for (int j = 0; j < 8; ++j) cols[j] = ridx[r * 32 + q * 8 + j];

    // ---- prefetch pass-0 gathers (both tiles) before weight packing ----
    float gA[8], gB[8];
    {
        const float* ra = x + (size_t)nbase * F_;
        const float* rb2 = ra + (size_t)128 * F_;
#pragma unroll
        for (int j = 0; j < 8; ++j) { gA[j] = ra[cols[j]]; gB[j] = rb2[cols[j]]; }
    }

    // ---- phase 1: pack masked weights into LDS A-frags ----
    {
        const float* W1b = W1 + (size_t)rb * 32 * 128;
        const float* M1b = M1 + (size_t)rb * 32 * 128;
        const float* W2b = W2 + (size_t)rb * 128 * 128;
        const float* M2s = M2;           // M2 identical across all networks
        const float* W3b = W3 + (size_t)rb * 128 * 64;
        const float* M3b = M3 + (size_t)rb * 128 * 64;

        const int pm = t & 127, pkq = t >> 7;   // 128-wide slabs
        const int qm = t & 63,  qkq = t >> 6;   // 64-wide superslabs
        // W3 column permutation (dest col -> source col)
        int osrc;
        {
            int dp = qm >> 1, pb = qm & 1;
            int dsrc = ((dp >> 1) & 3) * 8 + (dp >> 3) * 2 + (dp & 1);
            osrc = dsrc * 2 + pb;
        }

        float wv[2][8], mv[2][8];
        auto slab_load = [&](int s, float* wvv, float* mvv) {
            if (s == 0) {
                const float* wp = W1b + (size_t)(pkq * 8) * 128 + pm;
                const float* mp = M1b + (size_t)(pkq * 8) * 128 + pm;
#pragma unroll
                for (int e = 0; e < 8; ++e) { wvv[e] = wp[(size_t)e * 128]; mvv[e] = mp[(size_t)e * 128]; }
            } else if (s <= 4) {
                const float* wp = W2b + (size_t)((s - 1) * 32 + pkq * 8) * 128 + pm;
                const float* mp = M2s + (size_t)((s - 1) * 32 + pkq * 8) * 128 + pm;
#pragma unroll
                for (int e = 0; e < 8; ++e) { wvv[e] = wp[(size_t)e * 128]; mvv[e] = mp[(size_t)e * 128]; }
            } else {
                int ss = s - 5;
                const float* wp = W3b + (size_t)(ss * 64 + qkq * 8) * 64 + osrc;
                const float* mp = M3b + (size_t)(ss * 64 + qkq * 8) * 64 + osrc;
#pragma unroll
                for (int e = 0; e < 8; ++e) { wvv[e] = wp[(size_t)e * 64]; mvv[e] = mp[(size_t)e * 64]; }
            }
        };
        auto slab_store = [&](int s, const float* wvv, const float* mvv) {
            unsigned u0 = pk2(wvv[0] * mvv[0], wvv[1] * mvv[1]);
            unsigned u1 = pk2(wvv[2] * mvv[2], wvv[3] * mvv[3]);
            unsigned u2 = pk2(wvv[4] * mvv[4], wvv[5] * mvv[5]);
            unsigned u3 = pk2(wvv[6] * mvv[6], wvv[7] * mvv[7]);
            uint32x4 u = {u0, u1, u2, u3};
            if (s == 0) {
                int mt = pm >> 4, l = pkq * 16 + (pm & 15);
                *(uint32x4*)&WA1[(mt * 64 + l) * 8] = u;
            } else if (s <= 4) {
                int kt = s - 1, mt = pm >> 4, l = pkq * 16 + (pm & 15);
                *(uint32x4*)&WA2[((kt * 8 + mt) * 64 + l) * 8] = u;
            } else {
                int ss = s - 5;
                int kt = ss * 2 + (qkq >> 2), mt3 = qm >> 4, l = (qkq & 3) * 16 + (qm & 15);
                *(uint32x4*)&WA3[((kt * 4 + mt3) * 64 + l) * 8] = u;
            }
        };

        slab_load(0, wv[0], mv[0]);
#pragma unroll
        for (int s = 0; s < 7; ++s) {
            if (s < 6) slab_load(s + 1, wv[(s + 1) & 1], mv[(s + 1) & 1]);
            slab_store(s, wv[s & 1], mv[s & 1]);
        }
    }
    __syncthreads();                     // the ONLY barrier

    // ---- phase 2: 4 passes x 2 chunks, barrier-free ----
    const f32x4 z = {0.f, 0.f, 0.f, 0.f};
#pragma unroll 1
    for (int p = 0; p < 4; ++p) {
        // current x (fp32 kept for epilogue) + bf16 B-frags
        float xA[8], xB[8];
#pragma unroll
        for (int j = 0; j < 8; ++j) { xA[j] = gA[j]; xB[j] = gB[j]; }
        uint32x4 uA = {pk2(xA[0], xA[1]), pk2(xA[2], xA[3]), pk2(xA[4], xA[5]), pk2(xA[6], xA[7])};
        uint32x4 uB = {pk2(xB[0], xB[1]), pk2(xB[2], xB[3]), pk2(xB[4], xB[5]), pk2(xB[6], xB[7])};
        bf16x8 xbA = __builtin_bit_cast(bf16x8, uA);
        bf16x8 xbB = __builtin_bit_cast(bf16x8, uB);

        // h-store helper: C-layout quad -> B-frag layout, relu+bf16, b64 write
        auto hstore = [&](int tau, int mt, const f32x4& v) {
            int ktw = mt >> 1;
            int qw  = (mt & 1) * 2 + (q >> 1);
            int j0  = (q & 1) * 4;
            unsigned lo = pk2(fmaxf(v[0], 0.f), fmaxf(v[1], 0.f));
            unsigned hi = pk2(fmaxf(v[2], 0.f), fmaxf(v[3], 0.f));
            *(uint2*)&hwp[(((tau * 4 + ktw) * 64) + qw * 16 + c) * 8 + j0] = make_uint2(lo, hi);
        };

        // ---- GEMM1 (K=32): both tiles share the A-frags ----
        {
            bf16x8 a_[8];
#pragma unroll
            for (int mt = 0; mt < 8; ++mt)
                a_[mt] = *(const bf16x8*)&WA1[(mt * 64 + lane) * 8];
            f32x4 accA[8], accB[8];
#pragma unroll
            for (int mt = 0; mt < 8; ++mt) {
                accA[mt] = __builtin_amdgcn_mfma_f32_16x16x32_bf16(a_[mt], xbA, z, 0, 0, 0);
                accB[mt] = __builtin_amdgcn_mfma_f32_16x16x32_bf16(a_[mt], xbB, z, 0, 0, 0);
            }
#pragma unroll
            for (int mt = 0; mt < 8; ++mt) { hstore(0, mt, accA[mt]); hstore(1, mt, accB[mt]); }
        }

        // prefetch next pass's gathers (latency covered by GEMM2+GEMM3)
        if (p < 3) {
            const float* ra = x + (size_t)(nbase + (p + 1) * 256) * F_;
            const float* rb2 = ra + (size_t)128 * F_;
#pragma unroll
            for (int j = 0; j < 8; ++j) { gA[j] = ra[cols[j]]; gB[j] = rb2[cols[j]]; }
        }

        // ---- GEMM2 (K=128): h2 = relu(Wm2^T h1) ----
        {
            f32x4 acc2A[8], acc2B[8];
#pragma unroll
            for (int mt = 0; mt < 8; ++mt) { acc2A[mt] = z; acc2B[mt] = z; }
#pragma unroll
            for (int kt = 0; kt < 4; ++kt) {
                bf16x8 bA = *(const bf16x8*)&hwp[((0 + kt) * 64 + lane) * 8];
                bf16x8 bB = *(const bf16x8*)&hwp[((4 + kt) * 64 + lane) * 8];
                bf16x8 a2_[8];
#pragma unroll
                for (int mt = 0; mt < 8; ++mt)
                    a2_[mt] = *(const bf16x8*)&WA2[((kt * 8 + mt) * 64 + lane) * 8];
#pragma unroll
                for (int mt = 0; mt < 8; ++mt) {
                    acc2A[mt] = __builtin_amdgcn_mfma_f32_16x16x32_bf16(a2_[mt], bA, acc2A[mt], 0, 0, 0);
                    acc2B[mt] = __builtin_amdgcn_mfma_f32_16x16x32_bf16(a2_[mt], bB, acc2B[mt], 0, 0, 0);
                }
            }
            // overwrite h1 region with h2 (h1 dead; intra-wave lgkmcnt ordering)
#pragma unroll
            for (int mt = 0; mt < 8; ++mt) { hstore(0, mt, acc2A[mt]); hstore(1, mt, acc2B[mt]); }
        }

        // ---- GEMM3 (K=128, O=64 permuted) + MAF epilogue ----
        {
            f32x4 acc3A[4], acc3B[4];
#pragma unroll
            for (int mt3 = 0; mt3 < 4; ++mt3) { acc3A[mt3] = z; acc3B[mt3] = z; }
#pragma unroll
            for (int kt = 0; kt < 4; ++kt) {
                bf16x8 bA = *(const bf16x8*)&hwp[((0 + kt) * 64 + lane) * 8];
                bf16x8 bB = *(const bf16x8*)&hwp[((4 + kt) * 64 + lane) * 8];
                bf16x8 a3_[4];
#pragma unroll
                for (int mt3 = 0; mt3 < 4; ++mt3)
                    a3_[mt3] = *(const bf16x8*)&WA3[((kt * 4 + mt3) * 64 + lane) * 8];
#pragma unroll
                for (int mt3 = 0; mt3 < 4; ++mt3) {
                    acc3A[mt3] = __builtin_amdgcn_mfma_f32_16x16x32_bf16(a3_[mt3], bA, acc3A[mt3], 0, 0, 0);
                    acc3B[mt3] = __builtin_amdgcn_mfma_f32_16x16x32_bf16(a3_[mt3], bB, acc3B[mt3], 0, 0, 0);
                }
            }
            // epilogue: slot o = mt3*16 + q*4 + reg; pair rr = reg>>1 ->
            // source d = q*8 + mt3*2 + rr  ->  x = gx[mt3*2 + rr] (in regs!)
            float llA = 0.f, llB = 0.f;
#pragma unroll
            for (int mt3 = 0; mt3 < 4; ++mt3) {
#pragma unroll
                for (int rr = 0; rr < 2; ++rr) {
                    float shA = acc3A[mt3][rr * 2], lsA = acc3A[mt3][rr * 2 + 1];
                    float shB = acc3B[mt3][rr * 2], lsB = acc3B[mt3][rr * 2 + 1];
                    float u0 = (xA[mt3 * 2 + rr] - shA) * __expf(-lsA);
                    float u1 = (xB[mt3 * 2 + rr] - shB) * __expf(-lsB);
                    llA += fmaf(-0.5f * u0, u0, -HLP_ - lsA);
                    llB += fmaf(-0.5f * u1, u1, -HLP_ - lsB);
                }
            }
            // reduce across the 4 q-groups (lanes c, c+16, c+32, c+48)
            llA += __shfl_xor(llA, 16, 64);  llA += __shfl_xor(llA, 32, 64);
            llB += __shfl_xor(llB, 16, 64);  llB += __shfl_xor(llB, 32, 64);
            if (q == 0) {
                int n = nbase + p * 256;
                out[(size_t)n * 128 + rb]         = llA;
                out[(size_t)(n + 128) * 128 + rb] = llB;
            }
        }
    }
}

extern "C" void kernel_launch(void* const* d_in, const int* in_sizes, int n_in,
                              void* d_out, int out_size, void* d_ws, size_t ws_size,
                              hipStream_t stream) {
    const float* x   = (const float*)d_in[0];
    const float* W1  = (const float*)d_in[1];
    const float* W2  = (const float*)d_in[2];
    const float* W3  = (const float*)d_in[3];
    const float* M1  = (const float*)d_in[4];
    const float* M2  = (const float*)d_in[5];
    const float* M3  = (const float*)d_in[6];
    const int*  ridx = (const int*)d_in[7];
    float* out = (float*)d_out;

    flow_all<<<dim3(256), dim3(512), 0, stream>>>(x, W1, W2, W3, M1, M2, M3, ridx, out);
}